// Round 2
// baseline (756.125 us; speedup 1.0000x reference)
//
#include <hip/hip_runtime.h>
#include <hip/hip_bf16.h>

#define NODES   50000
#define E_TRAIN 600000
#define E_SCORE 200000

static __device__ __forceinline__ float bf2f(unsigned short u) {
    return __uint_as_float((unsigned int)u << 16);
}
static __device__ __forceinline__ unsigned short f2bf(float f) {
    __hip_bfloat16 h = __float2bfloat16(f);
    return *reinterpret_cast<unsigned short*>(&h);
}

// ---------------- dtype detection ----------------
// If x is bf16: u16[2i] is a bf16 of N(0,1) -> exponent field in [100,140] ~always.
// If x is fp32: u16[2i] is low mantissa bits -> uniform -> ~16% in range.
__global__ void detect_kernel(const unsigned int* __restrict__ xw, int* __restrict__ flag) {
    __shared__ int cnt;
    if (threadIdx.x == 0) cnt = 0;
    __syncthreads();
    unsigned int w = xw[threadIdx.x];
    unsigned short lo = (unsigned short)(w & 0xFFFFu);
    int e = (lo >> 7) & 0xFF;
    if (e >= 100 && e <= 140) atomicAdd(&cnt, 1);
    __syncthreads();
    if (threadIdx.x == 0) flag[0] = (cnt >= 150) ? 1 : 0;
}

// ---------------- weight normalization: any float dtype -> bf16 u16 ----------------
__global__ void convert_weights(const void* __restrict__ W1, const void* __restrict__ b1,
                                const void* __restrict__ W2, const void* __restrict__ b2,
                                unsigned short* __restrict__ W1u, unsigned short* __restrict__ b1u,
                                unsigned short* __restrict__ W2u, unsigned short* __restrict__ b2u,
                                const int* __restrict__ flag) {
    int i = blockIdx.x * blockDim.x + threadIdx.x;
    bool isbf = flag[0] != 0;
    if (i < 128 * 128)
        W1u[i] = isbf ? ((const unsigned short*)W1)[i] : f2bf(((const float*)W1)[i]);
    if (i < 128)
        b1u[i] = isbf ? ((const unsigned short*)b1)[i] : f2bf(((const float*)b1)[i]);
    if (i < 128 * 64)
        W2u[i] = isbf ? ((const unsigned short*)W2)[i] : f2bf(((const float*)W2)[i]);
    if (i < 64)
        b2u[i] = isbf ? ((const unsigned short*)b2)[i] : f2bf(((const float*)b2)[i]);
}

// ---------------- degree / dinv ----------------
__global__ void deg_kernel(const int* __restrict__ col, float* __restrict__ deg, int E) {
    int e = blockIdx.x * blockDim.x + threadIdx.x;
    if (e < E) unsafeAtomicAdd(&deg[col[e]], 1.0f);
}

__global__ void dinv_kernel(float* __restrict__ d, int n) {
    int i = blockIdx.x * blockDim.x + threadIdx.x;
    if (i < n) d[i] = rsqrtf(d[i] + 1.0f);   // +1 self-loop
}

// ---------------- GEMM1: C[n,128] = x[n,128] @ W1[128,128], fp32 out ----------------
__global__ __launch_bounds__(128) void gemm1_kernel(
    const void* __restrict__ A,
    const unsigned short* __restrict__ W,
    float* __restrict__ C, int nrows, const int* __restrict__ flag)
{
    __shared__ unsigned short wS[128 * 128];
    __shared__ float xS[128];
    const int tid = threadIdx.x;
    const bool isbf = flag[0] != 0;
    const unsigned short* Au = (const unsigned short*)A;
    const float* Af = (const float*)A;
    for (int i = tid; i < 128 * 128; i += 128) wS[i] = W[i];
    __syncthreads();
    const int row0 = blockIdx.x * 16;
    for (int r = 0; r < 16; ++r) {
        int row = row0 + r;                 // 50000 % 16 == 0, always in range
        xS[tid] = isbf ? bf2f(Au[(long)row * 128 + tid]) : Af[(long)row * 128 + tid];
        __syncthreads();
        float acc = 0.f;
        #pragma unroll 8
        for (int k = 0; k < 128; ++k)
            acc += xS[k] * bf2f(wS[k * 128 + tid]);
        C[(long)row * 128 + tid] = acc;
        __syncthreads();
    }
}

// ---------------- GEMM2: C[n,64] = h1[n,128](fp32) @ W2[128,64](bf16) ----------------
__global__ __launch_bounds__(256) void gemm2_kernel(
    const float* __restrict__ A,
    const unsigned short* __restrict__ W,
    float* __restrict__ C, int nrows)
{
    __shared__ unsigned short wS[128 * 64];
    __shared__ float xS[4][128];
    const int tid = threadIdx.x;
    const int col = tid & 63, sub = tid >> 6;
    for (int i = tid; i < 128 * 64; i += 256) wS[i] = W[i];
    __syncthreads();
    const int row0 = blockIdx.x * 16;
    for (int r = 0; r < 16; r += 4) {
        int row = row0 + r + sub;
        xS[sub][col]      = A[(long)row * 128 + col];
        xS[sub][col + 64] = A[(long)row * 128 + col + 64];
        __syncthreads();
        float acc = 0.f;
        #pragma unroll 8
        for (int k = 0; k < 128; ++k)
            acc += xS[sub][k] * bf2f(wS[k * 64 + col]);
        C[(long)row * 64 + col] = acc;
        __syncthreads();
    }
}

// ---------------- edge scatter: dst[d] += src[s] * dinv[s]*dinv[d] ----------------
template <int LOGF>
__global__ void scatter_kernel(const int* __restrict__ rows, const int* __restrict__ cols,
                               const float* __restrict__ dinv,
                               const float* __restrict__ src, float* __restrict__ dst,
                               long total)
{
    long idx = (long)blockIdx.x * blockDim.x + threadIdx.x;
    if (idx >= total) return;
    int e = (int)(idx >> LOGF);
    int f = (int)(idx & ((1 << LOGF) - 1));
    int s = rows[e], d = cols[e];
    float nrm = dinv[s] * dinv[d];
    unsafeAtomicAdd(&dst[((long)d << LOGF) + f], src[((long)s << LOGF) + f] * nrm);
}

// ---------------- finalize: acc += dinv[i]^2 * pre + bias; optional relu ----------
template <int LOGF, bool RELU>
__global__ void finalize_kernel(float* __restrict__ acc, const float* __restrict__ pre,
                                const float* __restrict__ dinv,
                                const unsigned short* __restrict__ bias, long total)
{
    long idx = (long)blockIdx.x * blockDim.x + threadIdx.x;
    if (idx >= total) return;
    int i = (int)(idx >> LOGF);
    int f = (int)(idx & ((1 << LOGF) - 1));
    float di = dinv[i];
    float v = acc[idx] + di * di * pre[idx] + bf2f(bias[f]);
    acc[idx] = RELU ? fmaxf(v, 0.f) : v;
}

// ---------------- scoring: out[e] = dot(h2[src], h2[dst]) over 64 dims ----------
__global__ void score_kernel(const int* __restrict__ pos, const int* __restrict__ neg,
                             const float* __restrict__ h2, void* __restrict__ out,
                             const int* __restrict__ flag)
{
    int e = blockIdx.x * blockDim.x + threadIdx.x;
    if (e >= 2 * E_SCORE) return;
    int s, d;
    if (e < E_SCORE) { s = pos[e];           d = pos[E_SCORE + e]; }
    else             { int i = e - E_SCORE; s = neg[i]; d = neg[E_SCORE + i]; }
    const float4* a = (const float4*)(h2 + (long)s * 64);
    const float4* b = (const float4*)(h2 + (long)d * 64);
    float acc = 0.f;
    #pragma unroll
    for (int q = 0; q < 16; ++q) {
        float4 av = a[q], bv = b[q];
        acc += av.x * bv.x + av.y * bv.y + av.z * bv.z + av.w * bv.w;
    }
    if (flag[0]) ((unsigned short*)out)[e] = f2bf(acc);
    else         ((float*)out)[e] = acc;
}

extern "C" void kernel_launch(void* const* d_in, const int* in_sizes, int n_in,
                              void* d_out, int out_size, void* d_ws, size_t ws_size,
                              hipStream_t stream) {
    const void* x      = d_in[0];                 // [N,128] bf16 OR fp32 (detected)
    const int*  etrain = (const int*)d_in[1];     // [2,E_TRAIN]
    const int*  pos    = (const int*)d_in[2];     // [2,E_SCORE]
    const int*  neg    = (const int*)d_in[3];     // [2,E_SCORE]
    const void* W1     = d_in[4];                 // [128,128]
    const void* b1     = d_in[5];                 // [128]
    const void* W2     = d_in[6];                 // [128,64]
    const void* b2     = d_in[7];                 // [64]

    // Workspace layout (byte offsets):
    char* base = (char*)d_ws;
    int*            flag = (int*)base;                               // 64 B
    float*          dinv = (float*)(base + 64);                      // 200,000 B
    unsigned short* W1u  = (unsigned short*)(base + 200064);         // 32,768 B
    unsigned short* b1u  = (unsigned short*)(base + 232832);         //    256 B
    unsigned short* W2u  = (unsigned short*)(base + 233088);         // 16,384 B
    unsigned short* b2u  = (unsigned short*)(base + 249472);         //    128 B
    float*          ht   = (float*)(base + 249600);                  // 25.6 MB
    float*          h1   = (float*)(base + 249600 + 25600000ULL);    // 25.6 MB
    float*          h2   = (float*)(base + 249600 + 51200000ULL);    // 12.8 MB
    // total ~64.25 MB

    const int* trow = etrain;            // sources
    const int* tcol = etrain + E_TRAIN;  // targets

    hipMemsetAsync(dinv, 0, NODES * sizeof(float), stream);
    hipMemsetAsync(h1, 0, (size_t)NODES * 128 * sizeof(float), stream);
    hipMemsetAsync(h2, 0, (size_t)NODES * 64 * sizeof(float), stream);

    detect_kernel<<<1, 256, 0, stream>>>((const unsigned int*)x, flag);
    convert_weights<<<64, 256, 0, stream>>>(W1, b1, W2, b2, W1u, b1u, W2u, b2u, flag);

    deg_kernel<<<(E_TRAIN + 255) / 256, 256, 0, stream>>>(tcol, dinv, E_TRAIN);
    dinv_kernel<<<(NODES + 255) / 256, 256, 0, stream>>>(dinv, NODES);

    // Layer 1
    gemm1_kernel<<<3125, 128, 0, stream>>>(x, W1u, ht, NODES, flag);
    {
        long total = (long)E_TRAIN * 128;
        scatter_kernel<7><<<(int)((total + 255) / 256), 256, 0, stream>>>(
            trow, tcol, dinv, ht, h1, total);
        long ntot = (long)NODES * 128;
        finalize_kernel<7, true><<<(int)((ntot + 255) / 256), 256, 0, stream>>>(
            h1, ht, dinv, b1u, ntot);
    }

    // Layer 2
    gemm2_kernel<<<3125, 256, 0, stream>>>(h1, W2u, ht, NODES);
    {
        long total = (long)E_TRAIN * 64;
        scatter_kernel<6><<<(int)((total + 255) / 256), 256, 0, stream>>>(
            trow, tcol, dinv, ht, h2, total);
        long ntot = (long)NODES * 64;
        finalize_kernel<6, false><<<(int)((ntot + 255) / 256), 256, 0, stream>>>(
            h2, ht, dinv, b2u, ntot);
    }

    score_kernel<<<(2 * E_SCORE + 255) / 256, 256, 0, stream>>>(pos, neg, h2, d_out, flag);
}

// Round 3
// 403.763 us; speedup vs baseline: 1.8727x; 1.8727x over previous
//
#include <hip/hip_runtime.h>
#include <hip/hip_bf16.h>

#define NODES   50000
#define E_TRAIN 600000
#define E_SCORE 200000

static __device__ __forceinline__ float bf2f(unsigned short u) {
    return __uint_as_float((unsigned int)u << 16);
}
static __device__ __forceinline__ unsigned short f2bf(float f) {
    __hip_bfloat16 h = __float2bfloat16(f);
    return *reinterpret_cast<unsigned short*>(&h);
}

// ---------------- dtype detection (x: bf16 vs fp32) ----------------
__global__ void detect_kernel(const unsigned int* __restrict__ xw, int* __restrict__ flag) {
    __shared__ int cnt;
    if (threadIdx.x == 0) cnt = 0;
    __syncthreads();
    unsigned int w = xw[threadIdx.x];
    unsigned short lo = (unsigned short)(w & 0xFFFFu);
    int e = (lo >> 7) & 0xFF;
    if (e >= 100 && e <= 140) atomicAdd(&cnt, 1);
    __syncthreads();
    if (threadIdx.x == 0) flag[0] = (cnt >= 150) ? 1 : 0;
}

// ---------------- weights -> fp32 (identity if already fp32) ----------------
__global__ void convert_weights(const void* __restrict__ W1, const void* __restrict__ b1,
                                const void* __restrict__ W2, const void* __restrict__ b2,
                                float* __restrict__ W1f, float* __restrict__ b1f,
                                float* __restrict__ W2f, float* __restrict__ b2f,
                                const int* __restrict__ flag) {
    int i = blockIdx.x * blockDim.x + threadIdx.x;
    bool isbf = flag[0] != 0;
    if (i < 128 * 128)
        W1f[i] = isbf ? bf2f(((const unsigned short*)W1)[i]) : ((const float*)W1)[i];
    if (i < 128)
        b1f[i] = isbf ? bf2f(((const unsigned short*)b1)[i]) : ((const float*)b1)[i];
    if (i < 128 * 64)
        W2f[i] = isbf ? bf2f(((const unsigned short*)W2)[i]) : ((const float*)W2)[i];
    if (i < 64)
        b2f[i] = isbf ? bf2f(((const unsigned short*)b2)[i]) : ((const float*)b2)[i];
}

// ---------------- degree counting (int) ----------------
__global__ void deg_kernel(const int* __restrict__ col, int* __restrict__ cnt, int E) {
    int e = blockIdx.x * blockDim.x + threadIdx.x;
    if (e < E) atomicAdd(&cnt[col[e]], 1);
}

__global__ void dinv_kernel(const int* __restrict__ cnt, float* __restrict__ dinv, int n) {
    int i = blockIdx.x * blockDim.x + threadIdx.x;
    if (i < n) dinv[i] = rsqrtf((float)cnt[i] + 1.0f);   // +1 self-loop
}

// ---------------- CSR build: 3-phase exclusive scan + bucket fill ----------------
__global__ void block_sum_kernel(const int* __restrict__ counts, int* __restrict__ partial, int n) {
    __shared__ int ts[256];
    int b = blockIdx.x, t = threadIdx.x;
    int base = b * 1024 + t * 4;
    int s = 0;
    #pragma unroll
    for (int i = 0; i < 4; ++i) { int idx = base + i; if (idx < n) s += counts[idx]; }
    ts[t] = s; __syncthreads();
    for (int off = 128; off > 0; off >>= 1) { if (t < off) ts[t] += ts[t + off]; __syncthreads(); }
    if (t == 0) partial[b] = ts[0];
}

__global__ void scan_partials_kernel(int* __restrict__ partial, int nb) {
    if (threadIdx.x == 0) {
        int run = 0;
        for (int i = 0; i < nb; ++i) { int v = partial[i]; partial[i] = run; run += v; }
    }
}

__global__ void scan_final_kernel(const int* __restrict__ counts, const int* __restrict__ pfx,
                                  int* __restrict__ row_start, int* __restrict__ cursor, int n) {
    __shared__ int ts[256];
    int b = blockIdx.x, t = threadIdx.x;
    int base = b * 1024 + t * 4;
    int c[4];
    #pragma unroll
    for (int i = 0; i < 4; ++i) { int idx = base + i; c[i] = (idx < n) ? counts[idx] : 0; }
    int sum = c[0] + c[1] + c[2] + c[3];
    ts[t] = sum; __syncthreads();
    for (int off = 1; off < 256; off <<= 1) {
        int v = (t >= off) ? ts[t - off] : 0;
        __syncthreads();
        ts[t] += v;
        __syncthreads();
    }
    int excl = ts[t] - sum + pfx[b];
    #pragma unroll
    for (int i = 0; i < 4; ++i) {
        int idx = base + i;
        if (idx < n) { row_start[idx] = excl; cursor[idx] = excl; }
        excl += c[i];
    }
}

__global__ void fill_csr_kernel(const int* __restrict__ row, const int* __restrict__ col,
                                int* __restrict__ cursor, int* __restrict__ esrc, int E) {
    int e = blockIdx.x * blockDim.x + threadIdx.x;
    if (e < E) {
        int d = col[e];
        int p = atomicAdd(&cursor[d], 1);
        esrc[p] = row[e];
    }
}

// ---------------- GEMM: C[n,FOUT] = dinv[row] * (A[n,128] @ W[128,FOUT]) ----------------
// 64x64 block tile, 4x4 per thread, K staged in 2 chunks of 64. LDS conflict-free.
template<int FOUT, bool MAYBE_BF16>
__global__ __launch_bounds__(256) void gemm_kernel(
    const void* __restrict__ A, const float* __restrict__ W,
    const float* __restrict__ dinv, float* __restrict__ C,
    const int* __restrict__ flag, int nrows)
{
    __shared__ float xS[64][68];   // xS[r][k]  (chunk of 64 k)
    __shared__ float wS[64][68];   // wS[k][c]  (chunk of 64 k, 64-col slice)
    const int t  = threadIdx.x;
    const int r0 = blockIdx.x * 64;
    const int c0 = blockIdx.y * 64;
    const bool isbf = MAYBE_BF16 ? (flag[0] != 0) : false;
    const float* Af = (const float*)A;
    const unsigned short* Au = (const unsigned short*)A;

    const int ci = (t & 15) * 4;
    const int ri = (t >> 4) * 4;
    float acc[4][4] = {};

    for (int kc = 0; kc < 2; ++kc) {
        // load x chunk: rows r0..r0+63, k = kc*64 .. +63  (lanes over k -> coalesced)
        #pragma unroll
        for (int i = 0; i < 16; ++i) {
            int flat = t + 256 * i;            // 4096 elems
            int r = flat >> 6, k = flat & 63;
            int row = r0 + r; if (row >= nrows) row = nrows - 1;
            long gidx = (long)row * 128 + kc * 64 + k;
            xS[r][k] = (MAYBE_BF16 && isbf) ? bf2f(Au[gidx]) : Af[gidx];
        }
        // load W chunk: k = kc*64..+63, c = c0..c0+63
        #pragma unroll
        for (int i = 0; i < 16; ++i) {
            int flat = t + 256 * i;
            int k = flat >> 6, c = flat & 63;
            wS[k][c] = W[(long)(kc * 64 + k) * FOUT + c0 + c];
        }
        __syncthreads();
        #pragma unroll 4
        for (int k = 0; k < 64; ++k) {
            float4 wv = *(const float4*)&wS[k][ci];
            float xr[4];
            #pragma unroll
            for (int a = 0; a < 4; ++a) xr[a] = xS[ri + a][k];
            float wc[4] = {wv.x, wv.y, wv.z, wv.w};
            #pragma unroll
            for (int a = 0; a < 4; ++a)
                #pragma unroll
                for (int b = 0; b < 4; ++b) acc[a][b] += xr[a] * wc[b];
        }
        __syncthreads();
    }
    #pragma unroll
    for (int a = 0; a < 4; ++a) {
        int row = r0 + ri + a;
        if (row < nrows) {
            float sc = dinv[row];
            float4 o = make_float4(acc[a][0] * sc, acc[a][1] * sc, acc[a][2] * sc, acc[a][3] * sc);
            *(float4*)&C[(long)row * FOUT + c0 + ci] = o;
        }
    }
}

// ---------------- gather-aggregate layer 1 (F=128), fused finalize+relu ----------------
__global__ __launch_bounds__(256) void gather1_kernel(
    const float* __restrict__ g1, const int* __restrict__ row_start,
    const int* __restrict__ counts, const int* __restrict__ esrc,
    const float* __restrict__ dinv, const float* __restrict__ bias,
    float* __restrict__ h1)
{
    int d = blockIdx.x * 4 + (threadIdx.x >> 6);
    int l = threadIdx.x & 63;
    int start = row_start[d], cnt = counts[d];
    float acc0 = 0.f, acc1 = 0.f;
    for (int j = 0; j < cnt; ++j) {
        int s = esrc[start + j];
        const float* gs = g1 + (long)s * 128;
        acc0 += gs[l];
        acc1 += gs[l + 64];
    }
    const float* gd = g1 + (long)d * 128;
    float di = dinv[d];
    float v0 = di * (acc0 + gd[l])      + bias[l];
    float v1 = di * (acc1 + gd[l + 64]) + bias[l + 64];
    h1[(long)d * 128 + l]      = fmaxf(v0, 0.f);
    h1[(long)d * 128 + 64 + l] = fmaxf(v1, 0.f);
}

// ---------------- gather-aggregate layer 2 (F=64), fused finalize ----------------
__global__ __launch_bounds__(256) void gather2_kernel(
    const float* __restrict__ g2, const int* __restrict__ row_start,
    const int* __restrict__ counts, const int* __restrict__ esrc,
    const float* __restrict__ dinv, const float* __restrict__ bias,
    float* __restrict__ h2)
{
    int d = blockIdx.x * 4 + (threadIdx.x >> 6);
    int l = threadIdx.x & 63;
    int start = row_start[d], cnt = counts[d];
    float acc = 0.f;
    for (int j = 0; j < cnt; ++j) {
        int s = esrc[start + j];
        acc += g2[(long)s * 64 + l];
    }
    float di = dinv[d];
    h2[(long)d * 64 + l] = di * (acc + g2[(long)d * 64 + l]) + bias[l];
}

// ---------------- scoring ----------------
__global__ void score_kernel(const int* __restrict__ pos, const int* __restrict__ neg,
                             const float* __restrict__ h2, void* __restrict__ out,
                             const int* __restrict__ flag)
{
    int e = blockIdx.x * blockDim.x + threadIdx.x;
    if (e >= 2 * E_SCORE) return;
    int s, d;
    if (e < E_SCORE) { s = pos[e];           d = pos[E_SCORE + e]; }
    else             { int i = e - E_SCORE; s = neg[i]; d = neg[E_SCORE + i]; }
    const float4* a = (const float4*)(h2 + (long)s * 64);
    const float4* b = (const float4*)(h2 + (long)d * 64);
    float acc = 0.f;
    #pragma unroll
    for (int q = 0; q < 16; ++q) {
        float4 av = a[q], bv = b[q];
        acc += av.x * bv.x + av.y * bv.y + av.z * bv.z + av.w * bv.w;
    }
    if (flag[0]) ((unsigned short*)out)[e] = f2bf(acc);
    else         ((float*)out)[e] = acc;
}

extern "C" void kernel_launch(void* const* d_in, const int* in_sizes, int n_in,
                              void* d_out, int out_size, void* d_ws, size_t ws_size,
                              hipStream_t stream) {
    const void* x      = d_in[0];                 // [N,128] fp32 (bf16 auto-detected)
    const int*  etrain = (const int*)d_in[1];     // [2,E_TRAIN]
    const int*  pos    = (const int*)d_in[2];
    const int*  neg    = (const int*)d_in[3];
    const void* W1     = d_in[4];
    const void* b1     = d_in[5];
    const void* W2     = d_in[6];
    const void* b2     = d_in[7];

    // Workspace layout (bytes):
    char* base = (char*)d_ws;
    int*   flag      = (int*)(base + 0);                 //      64
    float* dinv      = (float*)(base + 64);              // 200,000
    int*   counts    = (int*)(base + 200064);            // 200,000
    int*   row_start = (int*)(base + 400064);            // 200,000
    int*   cursor    = (int*)(base + 600064);            // 200,000
    int*   partial   = (int*)(base + 800064);            //     256
    float* W1f       = (float*)(base + 800320);          //  65,536
    float* b1f       = (float*)(base + 865856);          //     512
    float* W2f       = (float*)(base + 866368);          //  32,768
    float* b2f       = (float*)(base + 899136);          //     256
    int*   esrc      = (int*)(base + 899392);            // 2,400,000 -> 3,299,392
    float* g1        = (float*)(base + 3299840);         // 25,600,000 -> 28,899,840 (16B aligned)
    float* h1        = (float*)(base + 28899840);        // 25,600,000 -> 54,499,840
    float* g2        = g1;                               // reuse (g1 dead after gather1)
    float* h2        = (float*)(base + 3299840 + 12800000); // 16,099,840 (16B aligned)
    // total ~52 MB (< the 64.25 MB used successfully in round 2)

    const int* trow = etrain;            // sources
    const int* tcol = etrain + E_TRAIN;  // targets

    hipMemsetAsync(counts, 0, NODES * sizeof(int), stream);

    detect_kernel<<<1, 256, 0, stream>>>((const unsigned int*)x, flag);
    convert_weights<<<64, 256, 0, stream>>>(W1, b1, W2, b2, W1f, b1f, W2f, b2f, flag);

    deg_kernel<<<(E_TRAIN + 255) / 256, 256, 0, stream>>>(tcol, counts, E_TRAIN);
    dinv_kernel<<<(NODES + 255) / 256, 256, 0, stream>>>(counts, dinv, NODES);

    // CSR build
    const int NB = (NODES + 1023) / 1024;   // 49
    block_sum_kernel<<<NB, 256, 0, stream>>>(counts, partial, NODES);
    scan_partials_kernel<<<1, 64, 0, stream>>>(partial, NB);
    scan_final_kernel<<<NB, 256, 0, stream>>>(counts, partial, row_start, cursor, NODES);
    fill_csr_kernel<<<(E_TRAIN + 255) / 256, 256, 0, stream>>>(trow, tcol, cursor, esrc, E_TRAIN);

    // Layer 1: g1 = dinv * (x @ W1); h1 = relu(dinv*(agg+g1) + b1)
    gemm_kernel<128, true><<<dim3(782, 2), 256, 0, stream>>>(x, W1f, dinv, g1, flag, NODES);
    gather1_kernel<<<12500, 256, 0, stream>>>(g1, row_start, counts, esrc, dinv, b1f, h1);

    // Layer 2: g2 = dinv * (h1 @ W2); h2 = dinv*(agg+g2) + b2
    gemm_kernel<64, false><<<dim3(782, 1), 256, 0, stream>>>(h1, W2f, dinv, g2, flag, NODES);
    gather2_kernel<<<12500, 256, 0, stream>>>(g2, row_start, counts, esrc, dinv, b2f, h2);

    score_kernel<<<(2 * E_SCORE + 255) / 256, 256, 0, stream>>>(pos, neg, h2, d_out, flag);
}

// Round 4
// 290.117 us; speedup vs baseline: 2.6063x; 1.3917x over previous
//
#include <hip/hip_runtime.h>
#include <hip/hip_bf16.h>
#include <hip/hip_fp16.h>

#define NODES   50000
#define E_TRAIN 600000
#define E_SCORE 200000

static __device__ __forceinline__ float bf2f(unsigned short u) {
    return __uint_as_float((unsigned int)u << 16);
}
static __device__ __forceinline__ unsigned short f2bf(float f) {
    __hip_bfloat16 h = __float2bfloat16(f);
    return *reinterpret_cast<unsigned short*>(&h);
}
static __device__ __forceinline__ float2 u2f2(unsigned int u) {
    __half2 h = *reinterpret_cast<__half2*>(&u);
    return __half22float2(h);
}
static __device__ __forceinline__ unsigned int f22u(float a, float b) {
    __half2 h = __floats2half2_rn(a, b);
    return *reinterpret_cast<unsigned int*>(&h);
}

// ---------------- dtype detection (x: bf16 vs fp32) ----------------
__global__ void detect_kernel(const unsigned int* __restrict__ xw, int* __restrict__ flag) {
    __shared__ int cnt;
    if (threadIdx.x == 0) cnt = 0;
    __syncthreads();
    unsigned int w = xw[threadIdx.x];
    unsigned short lo = (unsigned short)(w & 0xFFFFu);
    int e = (lo >> 7) & 0xFF;
    if (e >= 100 && e <= 140) atomicAdd(&cnt, 1);
    __syncthreads();
    if (threadIdx.x == 0) flag[0] = (cnt >= 150) ? 1 : 0;
}

// ---------------- weights -> fp32 ----------------
__global__ void convert_weights(const void* __restrict__ W1, const void* __restrict__ b1,
                                const void* __restrict__ W2, const void* __restrict__ b2,
                                float* __restrict__ W1f, float* __restrict__ b1f,
                                float* __restrict__ W2f, float* __restrict__ b2f,
                                const int* __restrict__ flag) {
    int i = blockIdx.x * blockDim.x + threadIdx.x;
    bool isbf = flag[0] != 0;
    if (i < 128 * 128)
        W1f[i] = isbf ? bf2f(((const unsigned short*)W1)[i]) : ((const float*)W1)[i];
    if (i < 128)
        b1f[i] = isbf ? bf2f(((const unsigned short*)b1)[i]) : ((const float*)b1)[i];
    if (i < 128 * 64)
        W2f[i] = isbf ? bf2f(((const unsigned short*)W2)[i]) : ((const float*)W2)[i];
    if (i < 64)
        b2f[i] = isbf ? bf2f(((const unsigned short*)b2)[i]) : ((const float*)b2)[i];
}

// ---------------- degree counting ----------------
__global__ void deg_kernel(const int* __restrict__ col, int* __restrict__ cnt, int E) {
    int e = blockIdx.x * blockDim.x + threadIdx.x;
    if (e < E) atomicAdd(&cnt[col[e]], 1);
}

__global__ void dinv_kernel(const int* __restrict__ cnt, float* __restrict__ dinv, int n) {
    int i = blockIdx.x * blockDim.x + threadIdx.x;
    if (i < n) dinv[i] = rsqrtf((float)cnt[i] + 1.0f);
}

// ---------------- CSR build ----------------
__global__ void block_sum_kernel(const int* __restrict__ counts, int* __restrict__ partial, int n) {
    __shared__ int ts[256];
    int b = blockIdx.x, t = threadIdx.x;
    int base = b * 1024 + t * 4;
    int s = 0;
    #pragma unroll
    for (int i = 0; i < 4; ++i) { int idx = base + i; if (idx < n) s += counts[idx]; }
    ts[t] = s; __syncthreads();
    for (int off = 128; off > 0; off >>= 1) { if (t < off) ts[t] += ts[t + off]; __syncthreads(); }
    if (t == 0) partial[b] = ts[0];
}

__global__ void scan_partials_kernel(int* __restrict__ partial, int nb) {
    if (threadIdx.x == 0) {
        int run = 0;
        for (int i = 0; i < nb; ++i) { int v = partial[i]; partial[i] = run; run += v; }
    }
}

__global__ void scan_final_kernel(const int* __restrict__ counts, const int* __restrict__ pfx,
                                  int* __restrict__ row_start, int* __restrict__ cursor, int n) {
    __shared__ int ts[256];
    int b = blockIdx.x, t = threadIdx.x;
    int base = b * 1024 + t * 4;
    int c[4];
    #pragma unroll
    for (int i = 0; i < 4; ++i) { int idx = base + i; c[i] = (idx < n) ? counts[idx] : 0; }
    int sum = c[0] + c[1] + c[2] + c[3];
    ts[t] = sum; __syncthreads();
    for (int off = 1; off < 256; off <<= 1) {
        int v = (t >= off) ? ts[t - off] : 0;
        __syncthreads();
        ts[t] += v;
        __syncthreads();
    }
    int excl = ts[t] - sum + pfx[b];
    #pragma unroll
    for (int i = 0; i < 4; ++i) {
        int idx = base + i;
        if (idx < n) { row_start[idx] = excl; cursor[idx] = excl; }
        excl += c[i];
    }
}

__global__ void fill_csr_kernel(const int* __restrict__ row, const int* __restrict__ col,
                                int* __restrict__ cursor, int* __restrict__ esrc, int E) {
    int e = blockIdx.x * blockDim.x + threadIdx.x;
    if (e < E) {
        int d = col[e];
        int p = atomicAdd(&cursor[d], 1);
        esrc[p] = row[e];
    }
}

// ---------------- GEMM: Cg[n,FOUT](fp16) = dinv[row]*(A[n,128] @ W[128,FOUT]) ----------
template<int FOUT, bool MAYBE_BF16>
__global__ __launch_bounds__(256) void gemm_kernel(
    const void* __restrict__ A, const float* __restrict__ W,
    const float* __restrict__ dinv, unsigned int* __restrict__ Cg,
    const int* __restrict__ flag, int nrows)
{
    __shared__ float xS[64][68];
    __shared__ float wS[64][68];
    const int t  = threadIdx.x;
    const int r0 = blockIdx.x * 64;
    const int c0 = blockIdx.y * 64;
    const bool isbf = MAYBE_BF16 ? (flag[0] != 0) : false;
    const float* Af = (const float*)A;

    const int ci = (t & 15) * 4;
    const int ri = (t >> 4) * 4;
    float acc[4][4] = {};

    for (int kc = 0; kc < 2; ++kc) {
        if (MAYBE_BF16 && isbf) {
            const uint2* Ab = (const uint2*)A;   // 4 bf16 per uint2; row = 32 uint2
            #pragma unroll
            for (int i = 0; i < 4; ++i) {
                int flat = t + 256 * i;          // 1024 uint2
                int r = flat >> 4, p = flat & 15;
                int row = r0 + r; if (row >= nrows) row = nrows - 1;
                uint2 v = Ab[(long)row * 32 + kc * 16 + p];
                float4 f = make_float4(bf2f((unsigned short)(v.x & 0xFFFFu)),
                                       bf2f((unsigned short)(v.x >> 16)),
                                       bf2f((unsigned short)(v.y & 0xFFFFu)),
                                       bf2f((unsigned short)(v.y >> 16)));
                *(float4*)&xS[r][4 * p] = f;
            }
        } else {
            #pragma unroll
            for (int i = 0; i < 4; ++i) {
                int flat = t + 256 * i;          // 1024 float4
                int r = flat >> 4, p = flat & 15;
                int row = r0 + r; if (row >= nrows) row = nrows - 1;
                float4 v = *(const float4*)(Af + (long)row * 128 + kc * 64 + 4 * p);
                *(float4*)&xS[r][4 * p] = v;
            }
        }
        #pragma unroll
        for (int i = 0; i < 4; ++i) {
            int flat = t + 256 * i;              // 1024 float4
            int k = flat >> 4, p = flat & 15;
            float4 v = *(const float4*)(W + (long)(kc * 64 + k) * FOUT + c0 + 4 * p);
            *(float4*)&wS[k][4 * p] = v;
        }
        __syncthreads();
        #pragma unroll 4
        for (int k = 0; k < 64; ++k) {
            float4 wv = *(const float4*)&wS[k][ci];
            float xr[4];
            #pragma unroll
            for (int a = 0; a < 4; ++a) xr[a] = xS[ri + a][k];
            float wc[4] = {wv.x, wv.y, wv.z, wv.w};
            #pragma unroll
            for (int a = 0; a < 4; ++a)
                #pragma unroll
                for (int b = 0; b < 4; ++b) acc[a][b] += xr[a] * wc[b];
        }
        __syncthreads();
    }
    #pragma unroll
    for (int a = 0; a < 4; ++a) {
        int row = r0 + ri + a;
        if (row < nrows) {
            float sc = dinv[row];
            uint2 o;
            o.x = f22u(acc[a][0] * sc, acc[a][1] * sc);
            o.y = f22u(acc[a][2] * sc, acc[a][3] * sc);
            *(uint2*)&Cg[(long)row * (FOUT / 2) + ((c0 + ci) >> 1)] = o;
        }
    }
}

// ---------------- gather layer 1: wave per dest, fp16 rows of 256 B ----------------
__global__ __launch_bounds__(256) void gather1_kernel(
    const unsigned int* __restrict__ g1, const int* __restrict__ row_start,
    const int* __restrict__ counts, const int* __restrict__ esrc,
    const float* __restrict__ dinv, const float* __restrict__ bias,
    float* __restrict__ h1)
{
    int d = blockIdx.x * 4 + (threadIdx.x >> 6);
    int l = threadIdx.x & 63;
    int start = row_start[d], cnt = counts[d];
    float2 acc = make_float2(0.f, 0.f);
    int j = 0;
    for (; j + 4 <= cnt; j += 4) {
        int s0 = esrc[start + j + 0], s1 = esrc[start + j + 1];
        int s2 = esrc[start + j + 2], s3 = esrc[start + j + 3];
        unsigned int u0 = g1[(long)s0 * 64 + l];
        unsigned int u1 = g1[(long)s1 * 64 + l];
        unsigned int u2 = g1[(long)s2 * 64 + l];
        unsigned int u3 = g1[(long)s3 * 64 + l];
        float2 f0 = u2f2(u0), f1 = u2f2(u1), f2 = u2f2(u2), f3 = u2f2(u3);
        acc.x += (f0.x + f1.x) + (f2.x + f3.x);
        acc.y += (f0.y + f1.y) + (f2.y + f3.y);
    }
    for (; j < cnt; ++j) {
        float2 f = u2f2(g1[(long)esrc[start + j] * 64 + l]);
        acc.x += f.x; acc.y += f.y;
    }
    float2 gd = u2f2(g1[(long)d * 64 + l]);
    float di = dinv[d];
    float2 b = *(const float2*)&bias[2 * l];
    float v0 = di * (acc.x + gd.x) + b.x;
    float v1 = di * (acc.y + gd.y) + b.y;
    *(float2*)&h1[(long)d * 128 + 2 * l] = make_float2(fmaxf(v0, 0.f), fmaxf(v1, 0.f));
}

// ---------------- gather layer 2: half-wave per dest, fp16 rows of 128 B ----------
__global__ __launch_bounds__(256) void gather2_kernel(
    const unsigned int* __restrict__ g2, const int* __restrict__ row_start,
    const int* __restrict__ counts, const int* __restrict__ esrc,
    const float* __restrict__ dinv, const float* __restrict__ bias,
    unsigned int* __restrict__ h2)
{
    int d = blockIdx.x * 8 + (threadIdx.x >> 5);
    int l = threadIdx.x & 31;
    int start = row_start[d], cnt = counts[d];
    float2 acc = make_float2(0.f, 0.f);
    int j = 0;
    for (; j + 4 <= cnt; j += 4) {
        int s0 = esrc[start + j + 0], s1 = esrc[start + j + 1];
        int s2 = esrc[start + j + 2], s3 = esrc[start + j + 3];
        unsigned int u0 = g2[(long)s0 * 32 + l];
        unsigned int u1 = g2[(long)s1 * 32 + l];
        unsigned int u2 = g2[(long)s2 * 32 + l];
        unsigned int u3 = g2[(long)s3 * 32 + l];
        float2 f0 = u2f2(u0), f1 = u2f2(u1), f2 = u2f2(u2), f3 = u2f2(u3);
        acc.x += (f0.x + f1.x) + (f2.x + f3.x);
        acc.y += (f0.y + f1.y) + (f2.y + f3.y);
    }
    for (; j < cnt; ++j) {
        float2 f = u2f2(g2[(long)esrc[start + j] * 32 + l]);
        acc.x += f.x; acc.y += f.y;
    }
    float2 gd = u2f2(g2[(long)d * 32 + l]);
    float di = dinv[d];
    float2 b = *(const float2*)&bias[2 * l];
    float v0 = di * (acc.x + gd.x) + b.x;
    float v1 = di * (acc.y + gd.y) + b.y;
    h2[(long)d * 32 + l] = f22u(v0, v1);
}

// ---------------- scoring: fp16 h2 rows, 128 B each ----------------
__global__ void score_kernel(const int* __restrict__ pos, const int* __restrict__ neg,
                             const unsigned int* __restrict__ h2, void* __restrict__ out,
                             const int* __restrict__ flag)
{
    int e = blockIdx.x * blockDim.x + threadIdx.x;
    if (e >= 2 * E_SCORE) return;
    int s, d;
    if (e < E_SCORE) { s = pos[e];           d = pos[E_SCORE + e]; }
    else             { int i = e - E_SCORE; s = neg[i]; d = neg[E_SCORE + i]; }
    const uint4* A = (const uint4*)(h2 + (long)s * 32);
    const uint4* B = (const uint4*)(h2 + (long)d * 32);
    float acc = 0.f;
    #pragma unroll
    for (int q = 0; q < 8; ++q) {
        uint4 ua = A[q], ub = B[q];
        float2 a0 = u2f2(ua.x), b0 = u2f2(ub.x);
        float2 a1 = u2f2(ua.y), b1 = u2f2(ub.y);
        float2 a2 = u2f2(ua.z), b2 = u2f2(ub.z);
        float2 a3 = u2f2(ua.w), b3 = u2f2(ub.w);
        acc += a0.x * b0.x + a0.y * b0.y + a1.x * b1.x + a1.y * b1.y
             + a2.x * b2.x + a2.y * b2.y + a3.x * b3.x + a3.y * b3.y;
    }
    if (flag[0]) ((unsigned short*)out)[e] = f2bf(acc);
    else         ((float*)out)[e] = acc;
}

extern "C" void kernel_launch(void* const* d_in, const int* in_sizes, int n_in,
                              void* d_out, int out_size, void* d_ws, size_t ws_size,
                              hipStream_t stream) {
    const void* x      = d_in[0];
    const int*  etrain = (const int*)d_in[1];
    const int*  pos    = (const int*)d_in[2];
    const int*  neg    = (const int*)d_in[3];
    const void* W1     = d_in[4];
    const void* b1     = d_in[5];
    const void* W2     = d_in[6];
    const void* b2     = d_in[7];

    char* base = (char*)d_ws;
    int*          flag      = (int*)(base + 0);
    float*        dinv      = (float*)(base + 64);
    int*          counts    = (int*)(base + 200064);
    int*          row_start = (int*)(base + 400064);
    int*          cursor    = (int*)(base + 600064);
    int*          partial   = (int*)(base + 800064);
    float*        W1f       = (float*)(base + 800320);
    float*        b1f       = (float*)(base + 865856);
    float*        W2f       = (float*)(base + 866368);
    float*        b2f       = (float*)(base + 899136);
    int*          esrc      = (int*)(base + 899392);              // 2.4 MB
    unsigned int* g1        = (unsigned int*)(base + 3299392);    // fp16 [N][128] 12.8 MB
    float*        h1        = (float*)(base + 16099392);          // fp32 [N][128] 25.6 MB
    unsigned int* g2        = g1;                                 // reuse, fp16 [N][64]
    unsigned int* h2        = (unsigned int*)(base + 41699392);   // fp16 [N][64] 6.4 MB
    // total ~48.1 MB

    const int* trow = etrain;
    const int* tcol = etrain + E_TRAIN;

    hipMemsetAsync(counts, 0, NODES * sizeof(int), stream);

    detect_kernel<<<1, 256, 0, stream>>>((const unsigned int*)x, flag);
    convert_weights<<<64, 256, 0, stream>>>(W1, b1, W2, b2, W1f, b1f, W2f, b2f, flag);

    deg_kernel<<<(E_TRAIN + 255) / 256, 256, 0, stream>>>(tcol, counts, E_TRAIN);
    dinv_kernel<<<(NODES + 255) / 256, 256, 0, stream>>>(counts, dinv, NODES);

    const int NB = (NODES + 1023) / 1024;   // 49
    block_sum_kernel<<<NB, 256, 0, stream>>>(counts, partial, NODES);
    scan_partials_kernel<<<1, 64, 0, stream>>>(partial, NB);
    scan_final_kernel<<<NB, 256, 0, stream>>>(counts, partial, row_start, cursor, NODES);
    fill_csr_kernel<<<(E_TRAIN + 255) / 256, 256, 0, stream>>>(trow, tcol, cursor, esrc, E_TRAIN);

    gemm_kernel<128, true><<<dim3(782, 2), 256, 0, stream>>>(x, W1f, dinv, g1, flag, NODES);
    gather1_kernel<<<12500, 256, 0, stream>>>(g1, row_start, counts, esrc, dinv, b1f, h1);

    gemm_kernel<64, false><<<dim3(782, 1), 256, 0, stream>>>(h1, W2f, dinv, g2, flag, NODES);
    gather2_kernel<<<6250, 256, 0, stream>>>(g2, row_start, counts, esrc, dinv, b2f, h2);

    score_kernel<<<(2 * E_SCORE + 255) / 256, 256, 0, stream>>>(pos, neg, h2, d_out, flag);
}